// Round 3
// baseline (3212.965 us; speedup 1.0000x reference)
//
#include <hip/hip_runtime.h>
#include <math.h>

// Problem constants
#define B_ 256
#define T_ 2000
#define I_ 80
#define H_ 20
#define G_ 80      // 4*H
#define M_ 512000  // B*T

#define LOG2E 1.442695041f

// ---------------------------------------------------------------------------
// GEMM: XG[row][d*80+g] = sum_k X[row][k] * Wih[d][k][g] + Bias[d][g]
// Natural gate-major layout (o = gate*20 + j), matching w_ih directly.
// rows = B*T, K = 80 (layer0) or 40 (layer1), N = 160 (both dirs)
// tile: 96 rows x 160 cols, 8x8 micro-tile, K staged in chunks of 40.
// ---------------------------------------------------------------------------
template<int K>
__global__ __launch_bounds__(256) void gemm_xg(
    const float* __restrict__ X,     // (M, K)
    const float* __restrict__ Wih,   // (2, K, 80)
    const float* __restrict__ Bias,  // (2, 80)
    float* __restrict__ XG,          // (M, 160)
    int M)
{
    constexpr int KC = 40;
    __shared__ float ws[KC][164];   // [k][col], pad 160->164
    __shared__ float xs[KC][100];   // [k][row], pad 96->100
    __shared__ float bs[160];

    const int tid  = threadIdx.x;
    const int row0 = blockIdx.x * 96;
    const int tx = tid % 20;        // col group: cols 8*tx .. 8*tx+7
    const int ty = tid / 20;        // row group: rows 8*ty .. 8*ty+7 (ty<12 active)
    const bool run = (ty < 12);

    if (tid < 160) {
        int dd = (tid >= 80);
        bs[tid] = Bias[dd * 80 + (tid - 80 * dd)];
    }

    int nrows = M - row0; if (nrows > 96) nrows = 96;

    float acc[8][8];
    bool first = true;

    for (int kc = 0; kc < K; kc += KC) {
        // stage weights chunk: ws[i][c] = Wih[d][kc+i][g], c = d*80+g
        for (int idx = tid; idx < KC * 160; idx += 256) {
            int i = idx / 160, cc = idx - 160 * i;
            int dd = (cc >= 80), g = cc - 80 * dd;
            ws[i][cc] = Wih[(dd * K + kc + i) * 80 + g];
        }
        // stage x chunk, transposed: xs[k][r] = X[row0+r][kc+k]
        for (int i4 = tid; i4 < (96 * KC) / 4; i4 += 256) {
            int r = i4 / 10;
            int kk = (i4 - 10 * r) * 4;
            float4 v = make_float4(0.f, 0.f, 0.f, 0.f);
            if (r < nrows)
                v = *(const float4*)(X + (long long)(row0 + r) * K + kc + kk);
            xs[kk][r] = v.x; xs[kk + 1][r] = v.y; xs[kk + 2][r] = v.z; xs[kk + 3][r] = v.w;
        }
        __syncthreads();

        if (first) {
            first = false;
            float bv[8];
            #pragma unroll
            for (int cc = 0; cc < 8; ++cc) bv[cc] = bs[tx * 8 + cc];
            #pragma unroll
            for (int r = 0; r < 8; ++r)
                #pragma unroll
                for (int cc = 0; cc < 8; ++cc) acc[r][cc] = bv[cc];
        }

        if (run) {
            #pragma unroll 4
            for (int k = 0; k < KC; ++k) {
                float a[8], bb[8];
                *(float4*)&a[0]  = *(const float4*)&xs[k][ty * 8];
                *(float4*)&a[4]  = *(const float4*)&xs[k][ty * 8 + 4];
                *(float4*)&bb[0] = *(const float4*)&ws[k][tx * 8];
                *(float4*)&bb[4] = *(const float4*)&ws[k][tx * 8 + 4];
                #pragma unroll
                for (int r = 0; r < 8; ++r)
                    #pragma unroll
                    for (int cc = 0; cc < 8; ++cc)
                        acc[r][cc] = fmaf(a[r], bb[cc], acc[r][cc]);
            }
        }
        __syncthreads();
    }

    if (run) {
        #pragma unroll
        for (int r = 0; r < 8; ++r) {
            int row = row0 + ty * 8 + r;
            if (row < M) {
                float* dst = XG + (long long)row * 160 + tx * 8;
                *(float4*)(dst)     = *(float4*)&acc[r][0];
                *(float4*)(dst + 4) = *(float4*)&acc[r][4];
            }
        }
    }
}

// ---------------------------------------------------------------------------
// LSTM scan v3: one sequence per wave, OUTPUT-parallel.
// 80 gate pre-activations (o = gate*20+j) mapped to 64 lanes (slot1, o=lane)
// + a 16-wide second slot (o = 64 + (lane&15), lanes 0-15 meaningful).
//  - 40 FMA/step (vs 80), 40 weight VGPRs (vs 80) -> fits registers easily
//  - activation type is lane-constant: hoisted coefficient VGPRs, exp2-based
//  - c-update gather (unit j <- lanes j, j+20, j+40, go-lane) via 3 bpermute
//  - h broadcast: 20 v_readlane -> SGPRs (wave-uniform operands)
//  - 8-deep prefetch pipeline on the two per-step xg loads
// ---------------------------------------------------------------------------
__global__ __launch_bounds__(64, 1) void lstm_scan(
    const float* __restrict__ xg,    // (B,T,2,80): ((b*T+t)*2+d)*80 + o
    const float* __restrict__ w_hh,  // (2, 20, 80)
    float* __restrict__ h_out,       // (B, T, 40): [b][t][d*20+j]
    int T)
{
    const int sid  = blockIdx.x;          // 0..511
    const int b    = sid >> 1;
    const int d    = sid & 1;
    const int lane = threadIdx.x & 63;
    const int q    = lane & 15;

    // Weights: slot1 output o=lane; slot2 output o=64+q
    float w1[20], w2[20];
    const float* wb = w_hh + d * (H_ * G_);
    #pragma unroll
    for (int k = 0; k < 20; ++k) {
        w1[k] = wb[k * G_ + lane];
        w2[k] = wb[k * G_ + 64 + q];
    }

    // Slot1 activation coefficients (lane-constant, hoisted):
    // act(x) = pA * rcp(1 + exp2(pS*x)) + pB
    //   sigmoid: pS=-log2e, pA=1,  pB=0   (gates i,f,o: lanes <40 or >=60)
    //   tanh:    pS=+2log2e, pA=-2, pB=1  (gate g: lanes 40..59)
    const bool is_tanh1 = (lane >= 40 && lane < 60);
    const float pS1 = is_tanh1 ?  2.0f * LOG2E : -LOG2E;
    const float pA1 = is_tanh1 ? -2.0f : 1.0f;
    const float pB1 = is_tanh1 ?  1.0f : 0.0f;
    // Slot2 is always the o-gate (sigmoid): scalar constants.

    // bpermute byte-addresses (hoisted; meaningful on lanes 0..19)
    const int a_gf = 4 * ((lane + 20) & 63);
    const int a_gg = 4 * ((lane + 40) & 63);
    const int a_go = 4 * ((lane < 4) ? (60 + lane) : (lane - 4));

    // Wave-uniform h (SGPRs via readlane)
    float sh[20];
    #pragma unroll
    for (int k = 0; k < 20; ++k) sh[k] = 0.f;
    float c = 0.f;

    const int t0    = d ? (T - 1) : 0;
    const int rstep = d ? -160 : 160;     // (B,T,2,80): t-stride = 160 elems
    int off1 = ((b * T + t0) * 2 + d) * 80 + lane;       // slot1 xg index
    int off2 = ((b * T + t0) * 2 + d) * 80 + 64 + q;     // slot2 xg index

    float* hout = h_out + (long long)(b * T + t0) * 40 + d * 20 + lane;
    const int hstep = d ? -40 : 40;

    constexpr int PF = 8;
    float px1[PF], px2[PF];
    #pragma unroll
    for (int s = 0; s < PF; ++s) {
        px1[s] = xg[off1]; px2[s] = xg[off2];
        off1 += rstep; off2 += rstep;
    }

    for (int tb = 0; tb < T; tb += PF) {
        #pragma unroll
        for (int s = 0; s < PF; ++s) {
            const int t = tb + s;
            const float v1 = px1[s], v2 = px2[s];

            if (t + PF < T) {
                px1[s] = xg[off1]; px2[s] = xg[off2];
                off1 += rstep; off2 += rstep;
            }

            // slot1: pre-act for output o=lane; slot2: o=64+q
            float s0 = v1, s1 = 0.f, s2 = 0.f, s3 = 0.f;
            float r0 = v2, r1 = 0.f, r2 = 0.f, r3 = 0.f;
            #pragma unroll
            for (int k = 0; k < 20; k += 4) {
                s0 = fmaf(sh[k],     w1[k],     s0);
                s1 = fmaf(sh[k + 1], w1[k + 1], s1);
                s2 = fmaf(sh[k + 2], w1[k + 2], s2);
                s3 = fmaf(sh[k + 3], w1[k + 3], s3);
                r0 = fmaf(sh[k],     w2[k],     r0);
                r1 = fmaf(sh[k + 1], w2[k + 1], r1);
                r2 = fmaf(sh[k + 2], w2[k + 2], r2);
                r3 = fmaf(sh[k + 3], w2[k + 3], r3);
            }
            const float g1 = (s0 + s1) + (s2 + s3);
            const float g2 = (r0 + r1) + (r2 + r3);

            const float act1 = fmaf(pA1,
                __builtin_amdgcn_rcpf(1.0f + __builtin_amdgcn_exp2f(pS1 * g1)), pB1);
            const float act2 =
                __builtin_amdgcn_rcpf(1.0f + __builtin_amdgcn_exp2f(-LOG2E * g2));

            // gather gates for unit j=lane (meaningful on lanes 0..19)
            const float vgo_src = (lane >= 60) ? act1 : act2;
            const float gi = act1;
            const float gf = __uint_as_float(__builtin_amdgcn_ds_bpermute(
                                 a_gf, __float_as_uint(act1)));
            const float gg = __uint_as_float(__builtin_amdgcn_ds_bpermute(
                                 a_gg, __float_as_uint(act1)));
            const float go = __uint_as_float(__builtin_amdgcn_ds_bpermute(
                                 a_go, __float_as_uint(vgo_src)));

            c = fmaf(gf, c, gi * gg);
            // tanh(c) = 1 - 2*rcp(1+exp2(2*log2e*c))
            const float th = fmaf(-2.0f,
                __builtin_amdgcn_rcpf(1.0f + __builtin_amdgcn_exp2f(2.0f * LOG2E * c)),
                1.0f);
            const float hj = go * th;

            if (lane < H_) *hout = hj;
            hout += hstep;

            // broadcast h into wave-uniform SGPR copies
            #pragma unroll
            for (int k = 0; k < 20; ++k)
                sh[k] = __uint_as_float(__builtin_amdgcn_readlane(__float_as_uint(hj), k));
        }
    }
}

// ---------------------------------------------------------------------------
// FC: out[row] = dot(h1[row][0:40], fc_w) + fc_b.  256 rows per block.
// ---------------------------------------------------------------------------
__global__ __launch_bounds__(256) void fc_kernel(
    const float* __restrict__ H1,   // (M, 40)
    const float* __restrict__ Wf,   // (40,)
    const float* __restrict__ Bf,   // (1,)
    float* __restrict__ Out)        // (M,)
{
    __shared__ float ls[256 * 41];
    __shared__ float wl[40];
    const int tid = threadIdx.x;
    const long long row0 = (long long)blockIdx.x * 256;
    const float* src = H1 + row0 * 40;

    #pragma unroll
    for (int it = 0; it < 10; ++it) {
        int i4 = tid + it * 256;            // 0..2559
        float4 v = *(const float4*)(src + (long long)i4 * 4);
        int flat = i4 * 4;
        int r = flat / 40, jc = flat - 40 * r;  // 40%4==0: never straddles rows
        float* dp = &ls[r * 41 + jc];
        dp[0] = v.x; dp[1] = v.y; dp[2] = v.z; dp[3] = v.w;
    }
    if (tid < 40) wl[tid] = Wf[tid];
    __syncthreads();

    float acc = Bf[0];
    #pragma unroll
    for (int jc = 0; jc < 40; ++jc)
        acc = fmaf(ls[tid * 41 + jc], wl[jc], acc);
    Out[row0 + tid] = acc;
}

// ---------------------------------------------------------------------------
extern "C" void kernel_launch(void* const* d_in, const int* in_sizes, int n_in,
                              void* d_out, int out_size, void* d_ws, size_t ws_size,
                              hipStream_t stream) {
    const float* x     = (const float*)d_in[0];
    const float* wih0  = (const float*)d_in[1];
    const float* whh0  = (const float*)d_in[2];
    const float* b0    = (const float*)d_in[3];
    const float* wih1  = (const float*)d_in[4];
    const float* whh1  = (const float*)d_in[5];
    const float* b1    = (const float*)d_in[6];
    const float* fcw   = (const float*)d_in[7];
    const float* fcb   = (const float*)d_in[8];
    float* out = (float*)d_out;

    float* ws = (float*)d_ws;
    float* xg = ws;                        // B*T*2*80 = 81,920,000 floats
    float* h0 = ws + 81920000LL;           // B*T*40   = 20,480,000 floats
    float* h1 = ws + 102400000LL;          // B*T*40   = 20,480,000 floats

    const int M = M_;
    const int gemm_grid = (M + 95) / 96;   // 5334

    // Layer 0
    gemm_xg<80><<<dim3(gemm_grid), dim3(256), 0, stream>>>(x, wih0, b0, xg, M);
    lstm_scan<<<dim3(2 * B_), dim3(64), 0, stream>>>(xg, whh0, h0, T_);
    // Layer 1
    gemm_xg<40><<<dim3(gemm_grid), dim3(256), 0, stream>>>(h0, wih1, b1, xg, M);
    lstm_scan<<<dim3(2 * B_), dim3(64), 0, stream>>>(xg, whh1, h1, T_);
    // FC
    fc_kernel<<<dim3(M / 256), dim3(256), 0, stream>>>(h1, fcw, fcb, out);
}

// Round 4
// 3021.753 us; speedup vs baseline: 1.0633x; 1.0633x over previous
//
#include <hip/hip_runtime.h>
#include <math.h>

// Problem constants
#define B_ 256
#define T_ 2000
#define I_ 80
#define H_ 20
#define G_ 80      // 4*H
#define M_ 512000  // B*T

#define LOG2E 1.442695041f

typedef __attribute__((ext_vector_type(2))) float f32x2;

// quad_perm broadcast of quad-slot QS to all 4 lanes of each quad (VALU pipe!)
template<int QS>
__device__ __forceinline__ float quad_bcast(float x) {
    constexpr int ctrl = QS * 0x55;   // 0x00 / 0x55 / 0xAA / 0xFF
    return __uint_as_float((unsigned)__builtin_amdgcn_update_dpp(
        0, (int)__float_as_uint(x), ctrl, 0xF, 0xF, true));
}

// ---------------------------------------------------------------------------
// GEMM: XG[row][d*80 + j*4 + g] = sum_k X[row][k]*Wih[d][k][g*20+j] + B[d][g*20+j]
// UNIT-MAJOR gate interleave (col' = j*4+g): scan's unit j gates sit in
// adjacent columns -> adjacent lanes -> DPP quad gather. Permutation free here.
// ---------------------------------------------------------------------------
template<int K>
__global__ __launch_bounds__(256) void gemm_xg(
    const float* __restrict__ X,     // (M, K)
    const float* __restrict__ Wih,   // (2, K, 80)
    const float* __restrict__ Bias,  // (2, 80)
    float* __restrict__ XG,          // (M, 160) permuted cols
    int M)
{
    constexpr int KC = 40;
    __shared__ float ws[KC][164];
    __shared__ float xs[KC][100];
    __shared__ float bs[160];

    const int tid  = threadIdx.x;
    const int row0 = blockIdx.x * 96;
    const int tx = tid % 20;
    const int ty = tid / 20;
    const bool run = (ty < 12);

    if (tid < 160) {
        int dd = (tid >= 80);
        int r = tid - 80 * dd;
        int j = r >> 2, g = r & 3;
        bs[tid] = Bias[dd * 80 + g * 20 + j];
    }

    int nrows = M - row0; if (nrows > 96) nrows = 96;

    float acc[8][8];
    bool first = true;

    for (int kc = 0; kc < K; kc += KC) {
        for (int idx = tid; idx < KC * 160; idx += 256) {
            int i = idx / 160, cc = idx - 160 * i;
            int dd = (cc >= 80), r = cc - 80 * dd;
            int j = r >> 2, g = r & 3;
            ws[i][cc] = Wih[(dd * K + kc + i) * 80 + g * 20 + j];
        }
        for (int i4 = tid; i4 < (96 * KC) / 4; i4 += 256) {
            int r = i4 / 10;
            int kk = (i4 - 10 * r) * 4;
            float4 v = make_float4(0.f, 0.f, 0.f, 0.f);
            if (r < nrows)
                v = *(const float4*)(X + (long long)(row0 + r) * K + kc + kk);
            xs[kk][r] = v.x; xs[kk + 1][r] = v.y; xs[kk + 2][r] = v.z; xs[kk + 3][r] = v.w;
        }
        __syncthreads();

        if (first) {
            first = false;
            float bv[8];
            #pragma unroll
            for (int cc = 0; cc < 8; ++cc) bv[cc] = bs[tx * 8 + cc];
            #pragma unroll
            for (int r = 0; r < 8; ++r)
                #pragma unroll
                for (int cc = 0; cc < 8; ++cc) acc[r][cc] = bv[cc];
        }

        if (run) {
            #pragma unroll 4
            for (int k = 0; k < KC; ++k) {
                float a[8], bb[8];
                *(float4*)&a[0]  = *(const float4*)&xs[k][ty * 8];
                *(float4*)&a[4]  = *(const float4*)&xs[k][ty * 8 + 4];
                *(float4*)&bb[0] = *(const float4*)&ws[k][tx * 8];
                *(float4*)&bb[4] = *(const float4*)&ws[k][tx * 8 + 4];
                #pragma unroll
                for (int r = 0; r < 8; ++r)
                    #pragma unroll
                    for (int cc = 0; cc < 8; ++cc)
                        acc[r][cc] = fmaf(a[r], bb[cc], acc[r][cc]);
            }
        }
        __syncthreads();
    }

    if (run) {
        #pragma unroll
        for (int r = 0; r < 8; ++r) {
            int row = row0 + ty * 8 + r;
            if (row < M) {
                float* dst = XG + (long long)row * 160 + tx * 8;
                *(float4*)(dst)     = *(float4*)&acc[r][0];
                *(float4*)(dst + 4) = *(float4*)&acc[r][4];
            }
        }
    }
}

// ---------------------------------------------------------------------------
// LSTM scan v4: one sequence per wave, output-parallel, unit-major quads.
//  - lane L: slot1 = output unit j1=L>>2 gate g=L&3 (units 0..15);
//            slot2 = unit 16+(q>>2), gate q&3, q=L&15 (units 16..19, x4 dup)
//  - slot1+slot2 packed as float2 -> v_pk_fma_f32, 20 packed FMA/step
//  - activation type lane-constant (tanh iff (L&3)==2), exp2-based
//  - gate gather via 8 DPP quad_perm broadcasts (VALU pipe, no LDS!)
//  - c, tanh(c), h computed redundantly in all 4 quad lanes (no divergence)
//  - h broadcast: 20 v_readlane -> SGPRs
//  - amdgpu_waves_per_eu(1,1): pin occupancy, stop AGPR offload of weights
// ---------------------------------------------------------------------------
__attribute__((amdgpu_waves_per_eu(1, 1)))
__global__ __launch_bounds__(64, 1) void lstm_scan(
    const float* __restrict__ xg,    // (B,T,2,80) cols unit-major: j*4+g
    const float* __restrict__ w_hh,  // (2, 20, 80) natural (k, g*20+j)
    float* __restrict__ h_out,       // (B, T, 40): [b][t][d*20+j]
    int T)
{
    const int sid  = blockIdx.x;          // 0..511
    const int b    = sid >> 1;
    const int d    = sid & 1;
    const int lane = threadIdx.x & 63;
    const int q    = lane & 15;
    const int g    = lane & 3;            // gate id for BOTH slots
    const int j1   = lane >> 2;           // slot1 unit (0..15)
    const int j2   = 16 + (q >> 2);       // slot2 unit (16..19)

    // Packed weights: w12[k] = (W[k][g*20+j1], W[k][g*20+j2])
    f32x2 w12[20];
    const float* wb = w_hh + d * (H_ * G_);
    #pragma unroll
    for (int k = 0; k < 20; ++k) {
        w12[k].x = wb[k * G_ + g * 20 + j1];
        w12[k].y = wb[k * G_ + g * 20 + j2];
    }

    // Lane-constant activation coefficients: act(x) = pA*rcp(1+exp2(pS*x))+pB
    const bool is_tanh = (g == 2);
    const float pS = is_tanh ?  2.0f * LOG2E : -LOG2E;
    const float pA = is_tanh ? -2.0f : 1.0f;
    const float pB = is_tanh ?  1.0f : 0.0f;

    // Wave-uniform h (SGPRs via readlane)
    float sh[20];
    #pragma unroll
    for (int k = 0; k < 20; ++k) sh[k] = 0.f;
    float c1 = 0.f, c2 = 0.f;

    const int t0    = d ? (T - 1) : 0;
    const int rstep = d ? -160 : 160;
    const int base  = ((b * T + t0) * 2 + d) * 80;
    int off1 = base + lane;        // slot1 col' = lane
    int off2 = base + 64 + q;      // slot2 col' = 64+q

    // store plumbing: 20 storing lanes
    const bool p_st = (g == 0) || (g == 1 && lane < 16);
    const int  u    = (g == 1) ? j2 : j1;     // unit this lane stores
    float* hout = h_out + (long long)(b * T + t0) * 40 + d * 20 + u;
    const int hstep = d ? -40 : 40;

    constexpr int PF = 8;
    float px1[PF], px2[PF];
    #pragma unroll
    for (int s = 0; s < PF; ++s) {
        px1[s] = xg[off1]; px2[s] = xg[off2];
        off1 += rstep; off2 += rstep;
    }

    for (int tb = 0; tb < T; tb += PF) {
        #pragma unroll
        for (int s = 0; s < PF; ++s) {
            const int t = tb + s;
            const float v1 = px1[s], v2 = px2[s];

            if (t + PF < T) {
                px1[s] = xg[off1]; px2[s] = xg[off2];
                off1 += rstep; off2 += rstep;
            }

            // packed dot: 4 chains of 5 pk_fma
            f32x2 a0 = {v1, v2};
            f32x2 a1 = {0.f, 0.f}, a2 = {0.f, 0.f}, a3 = {0.f, 0.f};
            #pragma unroll
            for (int k = 0; k < 20; k += 4) {
                a0 = __builtin_elementwise_fma(w12[k],     (f32x2){sh[k],     sh[k]},     a0);
                a1 = __builtin_elementwise_fma(w12[k + 1], (f32x2){sh[k + 1], sh[k + 1]}, a1);
                a2 = __builtin_elementwise_fma(w12[k + 2], (f32x2){sh[k + 2], sh[k + 2]}, a2);
                a3 = __builtin_elementwise_fma(w12[k + 3], (f32x2){sh[k + 3], sh[k + 3]}, a3);
            }
            const f32x2 g12 = (a0 + a1) + (a2 + a3);

            // lane-typed activations (slot1 = .x, slot2 = .y)
            const float act1 = fmaf(pA,
                __builtin_amdgcn_rcpf(1.0f + __builtin_amdgcn_exp2f(pS * g12.x)), pB);
            const float act2 = fmaf(pA,
                __builtin_amdgcn_rcpf(1.0f + __builtin_amdgcn_exp2f(pS * g12.y)), pB);

            // quad gather via DPP (all lanes of quad get all 4 gates)
            const float gi1 = quad_bcast<0>(act1);
            const float gf1 = quad_bcast<1>(act1);
            const float gg1 = quad_bcast<2>(act1);
            const float go1 = quad_bcast<3>(act1);
            const float gi2 = quad_bcast<0>(act2);
            const float gf2 = quad_bcast<1>(act2);
            const float gg2 = quad_bcast<2>(act2);
            const float go2 = quad_bcast<3>(act2);

            // redundant per-quad c/h update (no divergence)
            c1 = fmaf(gf1, c1, gi1 * gg1);
            c2 = fmaf(gf2, c2, gi2 * gg2);
            const float th1 = fmaf(-2.0f,
                __builtin_amdgcn_rcpf(1.0f + __builtin_amdgcn_exp2f(2.0f * LOG2E * c1)), 1.0f);
            const float th2 = fmaf(-2.0f,
                __builtin_amdgcn_rcpf(1.0f + __builtin_amdgcn_exp2f(2.0f * LOG2E * c2)), 1.0f);
            const float h1 = go1 * th1;
            const float h2 = go2 * th2;

            // one predicated store: slot chosen per lane
            const float sv = (g == 1) ? h2 : h1;
            if (p_st) *hout = sv;
            hout += hstep;

            // broadcast h into wave-uniform SGPR copies:
            // units 0..15 from slot1 lanes 4j; units 16..19 from slot2 lanes 0,4,8,12
            #pragma unroll
            for (int k = 0; k < 16; ++k)
                sh[k] = __uint_as_float(__builtin_amdgcn_readlane(__float_as_uint(h1), 4 * k));
            #pragma unroll
            for (int k = 0; k < 4; ++k)
                sh[16 + k] = __uint_as_float(__builtin_amdgcn_readlane(__float_as_uint(h2), 4 * k));
        }
    }
}

// ---------------------------------------------------------------------------
// FC: out[row] = dot(h1[row][0:40], fc_w) + fc_b.  256 rows per block.
// ---------------------------------------------------------------------------
__global__ __launch_bounds__(256) void fc_kernel(
    const float* __restrict__ H1,   // (M, 40)
    const float* __restrict__ Wf,   // (40,)
    const float* __restrict__ Bf,   // (1,)
    float* __restrict__ Out)        // (M,)
{
    __shared__ float ls[256 * 41];
    __shared__ float wl[40];
    const int tid = threadIdx.x;
    const long long row0 = (long long)blockIdx.x * 256;
    const float* src = H1 + row0 * 40;

    #pragma unroll
    for (int it = 0; it < 10; ++it) {
        int i4 = tid + it * 256;
        float4 v = *(const float4*)(src + (long long)i4 * 4);
        int flat = i4 * 4;
        int r = flat / 40, jc = flat - 40 * r;
        float* dp = &ls[r * 41 + jc];
        dp[0] = v.x; dp[1] = v.y; dp[2] = v.z; dp[3] = v.w;
    }
    if (tid < 40) wl[tid] = Wf[tid];
    __syncthreads();

    float acc = Bf[0];
    #pragma unroll
    for (int jc = 0; jc < 40; ++jc)
        acc = fmaf(ls[tid * 41 + jc], wl[jc], acc);
    Out[row0 + tid] = acc;
}

// ---------------------------------------------------------------------------
extern "C" void kernel_launch(void* const* d_in, const int* in_sizes, int n_in,
                              void* d_out, int out_size, void* d_ws, size_t ws_size,
                              hipStream_t stream) {
    const float* x     = (const float*)d_in[0];
    const float* wih0  = (const float*)d_in[1];
    const float* whh0  = (const float*)d_in[2];
    const float* b0    = (const float*)d_in[3];
    const float* wih1  = (const float*)d_in[4];
    const float* whh1  = (const float*)d_in[5];
    const float* b1    = (const float*)d_in[6];
    const float* fcw   = (const float*)d_in[7];
    const float* fcb   = (const float*)d_in[8];
    float* out = (float*)d_out;

    float* ws = (float*)d_ws;
    float* xg = ws;                        // B*T*2*80 floats
    float* h0 = ws + 81920000LL;           // B*T*40 floats
    float* h1 = ws + 102400000LL;          // B*T*40 floats

    const int M = M_;
    const int gemm_grid = (M + 95) / 96;   // 5334

    // Layer 0
    gemm_xg<80><<<dim3(gemm_grid), dim3(256), 0, stream>>>(x, wih0, b0, xg, M);
    lstm_scan<<<dim3(2 * B_), dim3(64), 0, stream>>>(xg, whh0, h0, T_);
    // Layer 1
    gemm_xg<40><<<dim3(gemm_grid), dim3(256), 0, stream>>>(h0, wih1, b1, xg, M);
    lstm_scan<<<dim3(2 * B_), dim3(64), 0, stream>>>(xg, whh1, h1, T_);
    // FC
    fc_kernel<<<dim3(M / 256), dim3(256), 0, stream>>>(h1, fcw, fcb, out);
}

// Round 5
// 1959.523 us; speedup vs baseline: 1.6397x; 1.5421x over previous
//
#include <hip/hip_runtime.h>
#include <math.h>

// Problem constants
#define B_ 256
#define T_ 2000
#define I_ 80
#define H_ 20
#define G_ 80      // 4*H
#define M_ 512000  // B*T

#define LOG2E 1.442695041f

typedef __attribute__((ext_vector_type(2))) float f32x2;

__device__ __forceinline__ f32x2 mk2(float a, float b) { f32x2 r; r.x = a; r.y = b; return r; }

// ---------------------------------------------------------------------------
// GEMM: XG[row][d*80 + j*4 + g] = pS_g * (sum_k X[row][k]*Wih[d][k][g*20+j] + B[d][g*20+j])
// Unit-major gate interleave (col' = j*4+g) AND pre-scaled by the activation
// input scale pS_g (-log2e for sigmoid gates i,f,o; +2log2e for tanh gate g),
// so the scan's activations are rcp(1+exp2(x)) with no multiply.
// ---------------------------------------------------------------------------
template<int K>
__global__ __launch_bounds__(256) void gemm_xg(
    const float* __restrict__ X,     // (M, K)
    const float* __restrict__ Wih,   // (2, K, 80)
    const float* __restrict__ Bias,  // (2, 80)
    float* __restrict__ XG,          // (M, 160) permuted+scaled cols
    int M)
{
    constexpr int KC = 40;
    __shared__ float ws[KC][164];
    __shared__ float xs[KC][100];
    __shared__ float bs[160];

    const int tid  = threadIdx.x;
    const int row0 = blockIdx.x * 96;
    const int tx = tid % 20;
    const int ty = tid / 20;
    const bool run = (ty < 12);

    if (tid < 160) {
        int dd = (tid >= 80);
        int r = tid - 80 * dd;
        int j = r >> 2, g = r & 3;
        float sc = (g == 2) ? 2.0f * LOG2E : -LOG2E;
        bs[tid] = sc * Bias[dd * 80 + g * 20 + j];
    }

    int nrows = M - row0; if (nrows > 96) nrows = 96;

    float acc[8][8];
    bool first = true;

    for (int kc = 0; kc < K; kc += KC) {
        for (int idx = tid; idx < KC * 160; idx += 256) {
            int i = idx / 160, cc = idx - 160 * i;
            int dd = (cc >= 80), r = cc - 80 * dd;
            int j = r >> 2, g = r & 3;
            float sc = (g == 2) ? 2.0f * LOG2E : -LOG2E;
            ws[i][cc] = sc * Wih[(dd * K + kc + i) * 80 + g * 20 + j];
        }
        for (int i4 = tid; i4 < (96 * KC) / 4; i4 += 256) {
            int r = i4 / 10;
            int kk = (i4 - 10 * r) * 4;
            float4 v = make_float4(0.f, 0.f, 0.f, 0.f);
            if (r < nrows)
                v = *(const float4*)(X + (long long)(row0 + r) * K + kc + kk);
            xs[kk][r] = v.x; xs[kk + 1][r] = v.y; xs[kk + 2][r] = v.z; xs[kk + 3][r] = v.w;
        }
        __syncthreads();

        if (first) {
            first = false;
            float bv[8];
            #pragma unroll
            for (int cc = 0; cc < 8; ++cc) bv[cc] = bs[tx * 8 + cc];
            #pragma unroll
            for (int r = 0; r < 8; ++r)
                #pragma unroll
                for (int cc = 0; cc < 8; ++cc) acc[r][cc] = bv[cc];
        }

        if (run) {
            #pragma unroll 4
            for (int k = 0; k < KC; ++k) {
                float a[8], bb[8];
                *(float4*)&a[0]  = *(const float4*)&xs[k][ty * 8];
                *(float4*)&a[4]  = *(const float4*)&xs[k][ty * 8 + 4];
                *(float4*)&bb[0] = *(const float4*)&ws[k][tx * 8];
                *(float4*)&bb[4] = *(const float4*)&ws[k][tx * 8 + 4];
                #pragma unroll
                for (int r = 0; r < 8; ++r)
                    #pragma unroll
                    for (int cc = 0; cc < 8; ++cc)
                        acc[r][cc] = fmaf(a[r], bb[cc], acc[r][cc]);
            }
        }
        __syncthreads();
    }

    if (run) {
        #pragma unroll
        for (int r = 0; r < 8; ++r) {
            int row = row0 + ty * 8 + r;
            if (row < M) {
                float* dst = XG + (long long)row * 160 + tx * 8;
                *(float4*)(dst)     = *(float4*)&acc[r][0];
                *(float4*)(dst + 4) = *(float4*)&acc[r][4];
            }
        }
    }
}

// ---------------------------------------------------------------------------
// LSTM scan v5: TWO sequences per wave (fwd: lanes 0-19, bwd: lanes 32-51),
// unit-per-lane (v2 skeleton — the measured-fastest structure).
//  - weight REGISTERS shared: each lane loads its own (d, j) weights
//  - per-seq dot: K-pair packed v_pk_fma_f32 with wave-uniform h (SGPR pairs)
//    -> 80 pk_fma for BOTH sequences (= v2's issue count for ONE)
//  - after per-gate reduce, cndmask merges halves: activations, c-update,
//    tanh(c), h, store are SHARED instructions for both sequences
//  - activation input scales pre-folded into xg (GEMM) and w_hh registers
//  - two seqs' dependency chains interleave -> tail latency hidden
//  - padded xg: prefetch needs no bounds branch
// ---------------------------------------------------------------------------
__attribute__((amdgpu_waves_per_eu(1)))
__global__ __launch_bounds__(64) void lstm_scan(
    const float* __restrict__ xg,    // (B,T,2,20,4) scaled, unit-major
    const float* __restrict__ w_hh,  // (2, 20, 80) natural (k, g*20+j)
    float* __restrict__ h_out,       // (B, T, 40): [b][t][d*20+j]
    int T)
{
    const int b    = blockIdx.x;          // 0..255
    const int lane = threadIdx.x & 63;
    const int d    = lane >> 5;           // 0 = fwd (lanes 0-31), 1 = bwd
    const int j    = lane & 31;
    const bool act_lane = (j < H_);
    const int jj   = act_lane ? j : 0;
    const bool isB = (d == 1);

    // Pre-scaled packed recurrent weights: w[g][i] = (pS_g*W[2i][g*20+j], pS_g*W[2i+1][g*20+j])
    // Same registers hold fwd weights on lanes 0-31 and bwd weights on 32-63.
    f32x2 w[4][10];
    const float* wb = w_hh + d * (H_ * G_);
    #pragma unroll
    for (int g = 0; g < 4; ++g) {
        const float sc = (g == 2) ? 2.0f * LOG2E : -LOG2E;
        #pragma unroll
        for (int i = 0; i < 10; ++i)
            w[g][i] = mk2(sc * wb[(2 * i) * G_ + g * 20 + jj],
                          sc * wb[(2 * i + 1) * G_ + g * 20 + jj]);
    }

    // Wave-uniform h for both sequences (SGPRs via readlane)
    float shA[20], shB[20];
    #pragma unroll
    for (int k = 0; k < 20; ++k) { shA[k] = 0.f; shB[k] = 0.f; }
    float c = 0.f;   // fwd c on lanes 0-19, bwd c on lanes 32-51

    const int t0    = isB ? (T - 1) : 0;
    const int rstep = isB ? -160 : 160;
    const float* pf = xg + ((long long)(b * T + t0) * 2 + d) * 80 + 4 * jj;

    float* hout = h_out + (long long)(b * T + t0) * 40 + d * 20 + jj;
    const int hstep = isB ? -40 : 40;

    constexpr int PF = 4;
    float4 px[PF];
    #pragma unroll
    for (int s = 0; s < PF; ++s) { px[s] = *(const float4*)pf; pf += rstep; }

    for (int tb = 0; tb < T; tb += PF) {
        #pragma unroll
        for (int s = 0; s < PF; ++s) {
            const float4 v = px[s];
            // always-prefetch t+PF (xg padded on both ends — no branch)
            px[s] = *(const float4*)pf; pf += rstep;

            // 8 independent pk-chains (4 gates x 2 seqs), depth 10
            f32x2 aA[4], aB[4];
            aA[0] = mk2(v.x, 0.f); aA[1] = mk2(v.y, 0.f);
            aA[2] = mk2(v.z, 0.f); aA[3] = mk2(v.w, 0.f);
            #pragma unroll
            for (int g = 0; g < 4; ++g) aB[g] = aA[g];
            #pragma unroll
            for (int i = 0; i < 10; ++i) {
                const f32x2 ha = mk2(shA[2 * i], shA[2 * i + 1]);
                const f32x2 hb = mk2(shB[2 * i], shB[2 * i + 1]);
                #pragma unroll
                for (int g = 0; g < 4; ++g) {
                    aA[g] = __builtin_elementwise_fma(w[g][i], ha, aA[g]);
                    aB[g] = __builtin_elementwise_fma(w[g][i], hb, aB[g]);
                }
            }
            // per-gate reduce + merge halves (lane-half selects its sequence)
            float m[4];
            #pragma unroll
            for (int g = 0; g < 4; ++g) {
                const float sA = aA[g].x + aA[g].y;
                const float sB = aB[g].x + aB[g].y;
                m[g] = isB ? sB : sA;
            }

            // shared activations (inputs pre-scaled: sigmoid = rcp(1+exp2(x)))
            const float gi = __builtin_amdgcn_rcpf(1.0f + __builtin_amdgcn_exp2f(m[0]));
            const float gf = __builtin_amdgcn_rcpf(1.0f + __builtin_amdgcn_exp2f(m[1]));
            const float gg = fmaf(-2.0f,
                __builtin_amdgcn_rcpf(1.0f + __builtin_amdgcn_exp2f(m[2])), 1.0f);
            const float go = __builtin_amdgcn_rcpf(1.0f + __builtin_amdgcn_exp2f(m[3]));

            c = fmaf(gf, c, gi * gg);
            const float th = fmaf(-2.0f,
                __builtin_amdgcn_rcpf(1.0f + __builtin_amdgcn_exp2f(2.0f * LOG2E * c)), 1.0f);
            const float hj = go * th;

            if (act_lane) *hout = hj;
            hout += hstep;

            // broadcast both sequences' h into wave-uniform copies
            #pragma unroll
            for (int k = 0; k < 20; ++k) {
                shA[k] = __uint_as_float(__builtin_amdgcn_readlane(__float_as_uint(hj), k));
                shB[k] = __uint_as_float(__builtin_amdgcn_readlane(__float_as_uint(hj), 32 + k));
            }
        }
    }
}

// ---------------------------------------------------------------------------
// FC: out[row] = dot(h1[row][0:40], fc_w) + fc_b.  256 rows per block.
// ---------------------------------------------------------------------------
__global__ __launch_bounds__(256) void fc_kernel(
    const float* __restrict__ H1,   // (M, 40)
    const float* __restrict__ Wf,   // (40,)
    const float* __restrict__ Bf,   // (1,)
    float* __restrict__ Out)        // (M,)
{
    __shared__ float ls[256 * 41];
    __shared__ float wl[40];
    const int tid = threadIdx.x;
    const long long row0 = (long long)blockIdx.x * 256;
    const float* src = H1 + row0 * 40;

    #pragma unroll
    for (int it = 0; it < 10; ++it) {
        int i4 = tid + it * 256;
        float4 v = *(const float4*)(src + (long long)i4 * 4);
        int flat = i4 * 4;
        int r = flat / 40, jc = flat - 40 * r;
        float* dp = &ls[r * 41 + jc];
        dp[0] = v.x; dp[1] = v.y; dp[2] = v.z; dp[3] = v.w;
    }
    if (tid < 40) wl[tid] = Wf[tid];
    __syncthreads();

    float acc = Bf[0];
    #pragma unroll
    for (int jc = 0; jc < 40; ++jc)
        acc = fmaf(ls[tid * 41 + jc], wl[jc], acc);
    Out[row0 + tid] = acc;
}

// ---------------------------------------------------------------------------
extern "C" void kernel_launch(void* const* d_in, const int* in_sizes, int n_in,
                              void* d_out, int out_size, void* d_ws, size_t ws_size,
                              hipStream_t stream) {
    const float* x     = (const float*)d_in[0];
    const float* wih0  = (const float*)d_in[1];
    const float* whh0  = (const float*)d_in[2];
    const float* b0    = (const float*)d_in[3];
    const float* wih1  = (const float*)d_in[4];
    const float* whh1  = (const float*)d_in[5];
    const float* b1    = (const float*)d_in[6];
    const float* fcw   = (const float*)d_in[7];
    const float* fcb   = (const float*)d_in[8];
    float* out = (float*)d_out;

    // Workspace layout (floats), with 1024-float pads around xg so the scan's
    // unconditional prefetch (±4 steps = ±640 floats) never leaves d_ws.
    float* ws = (float*)d_ws;
    float* xg = ws + 1024;                   // B*T*2*80 = 81,920,000 floats
    float* h0 = xg + 81920000LL + 1024;      // B*T*40   = 20,480,000 floats
    float* h1 = h0 + 20480000LL;             // B*T*40   = 20,480,000 floats
    // total ≈ 491.5 MB + 8 KB

    const int M = M_;
    const int gemm_grid = (M + 95) / 96;     // 5334

    // Layer 0
    gemm_xg<80><<<dim3(gemm_grid), dim3(256), 0, stream>>>(x, wih0, b0, xg, M);
    lstm_scan<<<dim3(B_), dim3(64), 0, stream>>>(xg, whh0, h0, T_);
    // Layer 1
    gemm_xg<40><<<dim3(gemm_grid), dim3(256), 0, stream>>>(h0, wih1, b1, xg, M);
    lstm_scan<<<dim3(B_), dim3(64), 0, stream>>>(xg, whh1, h1, T_);
    // FC
    fc_kernel<<<dim3(M / 256), dim3(256), 0, stream>>>(h1, fcw, fcb, out);
}

// Round 6
// 1909.005 us; speedup vs baseline: 1.6831x; 1.0265x over previous
//
#include <hip/hip_runtime.h>
#include <math.h>

// Problem constants
#define B_ 256
#define T_ 2000
#define I_ 80
#define H_ 20
#define G_ 80      // 4*H
#define M_ 512000  // B*T

#define LOG2E 1.442695041f

typedef __attribute__((ext_vector_type(2))) float f32x2;

__device__ __forceinline__ f32x2 mk2(float a, float b) { f32x2 r; r.x = a; r.y = b; return r; }

// ---------------------------------------------------------------------------
// GEMM: XG[row][d*80 + j*4 + g] = pS_g * (sum_k X[row][k]*Wih[d][k][g*20+j] + B[d][g*20+j])
// Unit-major gate interleave (col' = j*4+g), pre-scaled by the activation
// input scale pS_g (-log2e sigmoid / +2log2e tanh) so scan activations are
// rcp(1+exp2(x)) with no multiply.
// ---------------------------------------------------------------------------
template<int K>
__global__ __launch_bounds__(256) void gemm_xg(
    const float* __restrict__ X,     // (M, K)
    const float* __restrict__ Wih,   // (2, K, 80)
    const float* __restrict__ Bias,  // (2, 80)
    float* __restrict__ XG,          // (M, 160) permuted+scaled cols
    int M)
{
    constexpr int KC = 40;
    __shared__ float ws[KC][164];
    __shared__ float xs[KC][100];
    __shared__ float bs[160];

    const int tid  = threadIdx.x;
    const int row0 = blockIdx.x * 96;
    const int tx = tid % 20;
    const int ty = tid / 20;
    const bool run = (ty < 12);

    if (tid < 160) {
        int dd = (tid >= 80);
        int r = tid - 80 * dd;
        int j = r >> 2, g = r & 3;
        float sc = (g == 2) ? 2.0f * LOG2E : -LOG2E;
        bs[tid] = sc * Bias[dd * 80 + g * 20 + j];
    }

    int nrows = M - row0; if (nrows > 96) nrows = 96;

    float acc[8][8];
    bool first = true;

    for (int kc = 0; kc < K; kc += KC) {
        for (int idx = tid; idx < KC * 160; idx += 256) {
            int i = idx / 160, cc = idx - 160 * i;
            int dd = (cc >= 80), r = cc - 80 * dd;
            int j = r >> 2, g = r & 3;
            float sc = (g == 2) ? 2.0f * LOG2E : -LOG2E;
            ws[i][cc] = sc * Wih[(dd * K + kc + i) * 80 + g * 20 + j];
        }
        for (int i4 = tid; i4 < (96 * KC) / 4; i4 += 256) {
            int r = i4 / 10;
            int kk = (i4 - 10 * r) * 4;
            float4 v = make_float4(0.f, 0.f, 0.f, 0.f);
            if (r < nrows)
                v = *(const float4*)(X + (long long)(row0 + r) * K + kc + kk);
            xs[kk][r] = v.x; xs[kk + 1][r] = v.y; xs[kk + 2][r] = v.z; xs[kk + 3][r] = v.w;
        }
        __syncthreads();

        if (first) {
            first = false;
            float bv[8];
            #pragma unroll
            for (int cc = 0; cc < 8; ++cc) bv[cc] = bs[tx * 8 + cc];
            #pragma unroll
            for (int r = 0; r < 8; ++r)
                #pragma unroll
                for (int cc = 0; cc < 8; ++cc) acc[r][cc] = bv[cc];
        }

        if (run) {
            #pragma unroll 4
            for (int k = 0; k < KC; ++k) {
                float a[8], bb[8];
                *(float4*)&a[0]  = *(const float4*)&xs[k][ty * 8];
                *(float4*)&a[4]  = *(const float4*)&xs[k][ty * 8 + 4];
                *(float4*)&bb[0] = *(const float4*)&ws[k][tx * 8];
                *(float4*)&bb[4] = *(const float4*)&ws[k][tx * 8 + 4];
                #pragma unroll
                for (int r = 0; r < 8; ++r)
                    #pragma unroll
                    for (int cc = 0; cc < 8; ++cc)
                        acc[r][cc] = fmaf(a[r], bb[cc], acc[r][cc]);
            }
        }
        __syncthreads();
    }

    if (run) {
        #pragma unroll
        for (int r = 0; r < 8; ++r) {
            int row = row0 + ty * 8 + r;
            if (row < M) {
                float* dst = XG + (long long)row * 160 + tx * 8;
                *(float4*)(dst)     = *(float4*)&acc[r][0];
                *(float4*)(dst + 4) = *(float4*)&acc[r][4];
            }
        }
    }
}

// ---------------------------------------------------------------------------
// LSTM scan v6 = v5 + PF=8 (deeper prefetch to cover ~900-cyc load latency).
// TWO sequences per wave (fwd: lanes 0-19, bwd: lanes 32-51), unit-per-lane.
//  - per-seq dot: K-pair packed v_pk_fma_f32 with wave-uniform h (SGPR pairs)
//  - cndmask merges halves: activations/c/tanh/h/store SHARED for both seqs
//  - activation input scales pre-folded into xg (GEMM) and w_hh registers
//  - 8-deep unconditional prefetch (xg padded both ends)
// ---------------------------------------------------------------------------
__attribute__((amdgpu_waves_per_eu(1)))
__global__ __launch_bounds__(64) void lstm_scan(
    const float* __restrict__ xg,    // (B,T,2,20,4) scaled, unit-major
    const float* __restrict__ w_hh,  // (2, 20, 80) natural (k, g*20+j)
    float* __restrict__ h_out,       // (B, T, 40): [b][t][d*20+j]
    int T)
{
    const int b    = blockIdx.x;          // 0..255
    const int lane = threadIdx.x & 63;
    const int d    = lane >> 5;           // 0 = fwd (lanes 0-31), 1 = bwd
    const int j    = lane & 31;
    const bool act_lane = (j < H_);
    const int jj   = act_lane ? j : 0;
    const bool isB = (d == 1);

    // Pre-scaled packed recurrent weights (per-half values in same registers)
    f32x2 w[4][10];
    const float* wb = w_hh + d * (H_ * G_);
    #pragma unroll
    for (int g = 0; g < 4; ++g) {
        const float sc = (g == 2) ? 2.0f * LOG2E : -LOG2E;
        #pragma unroll
        for (int i = 0; i < 10; ++i)
            w[g][i] = mk2(sc * wb[(2 * i) * G_ + g * 20 + jj],
                          sc * wb[(2 * i + 1) * G_ + g * 20 + jj]);
    }

    // Wave-uniform h for both sequences (SGPRs via readlane)
    float shA[20], shB[20];
    #pragma unroll
    for (int k = 0; k < 20; ++k) { shA[k] = 0.f; shB[k] = 0.f; }
    float c = 0.f;   // fwd c on lanes 0-19, bwd c on lanes 32-51

    const int t0    = isB ? (T - 1) : 0;
    const int rstep = isB ? -160 : 160;
    const float* pf = xg + ((long long)(b * T + t0) * 2 + d) * 80 + 4 * jj;

    float* hout = h_out + (long long)(b * T + t0) * 40 + d * 20 + jj;
    const int hstep = isB ? -40 : 40;

    constexpr int PF = 8;   // 8-step lookahead: distance ~8*step >> 900 cyc
    float4 px[PF];
    #pragma unroll
    for (int s = 0; s < PF; ++s) { px[s] = *(const float4*)pf; pf += rstep; }

    for (int tb = 0; tb < T; tb += PF) {
        #pragma unroll
        for (int s = 0; s < PF; ++s) {
            const float4 v = px[s];
            // always-prefetch t+PF (xg padded on both ends — no branch)
            px[s] = *(const float4*)pf; pf += rstep;

            // 8 independent pk-chains (4 gates x 2 seqs), depth 10
            f32x2 aA[4], aB[4];
            aA[0] = mk2(v.x, 0.f); aA[1] = mk2(v.y, 0.f);
            aA[2] = mk2(v.z, 0.f); aA[3] = mk2(v.w, 0.f);
            #pragma unroll
            for (int g = 0; g < 4; ++g) aB[g] = aA[g];
            #pragma unroll
            for (int i = 0; i < 10; ++i) {
                const f32x2 ha = mk2(shA[2 * i], shA[2 * i + 1]);
                const f32x2 hb = mk2(shB[2 * i], shB[2 * i + 1]);
                #pragma unroll
                for (int g = 0; g < 4; ++g) {
                    aA[g] = __builtin_elementwise_fma(w[g][i], ha, aA[g]);
                    aB[g] = __builtin_elementwise_fma(w[g][i], hb, aB[g]);
                }
            }
            // per-gate reduce + merge halves
            float m[4];
            #pragma unroll
            for (int g = 0; g < 4; ++g) {
                const float sA = aA[g].x + aA[g].y;
                const float sB = aB[g].x + aB[g].y;
                m[g] = isB ? sB : sA;
            }

            // shared activations (inputs pre-scaled: sigmoid = rcp(1+exp2(x)))
            const float gi = __builtin_amdgcn_rcpf(1.0f + __builtin_amdgcn_exp2f(m[0]));
            const float gf = __builtin_amdgcn_rcpf(1.0f + __builtin_amdgcn_exp2f(m[1]));
            const float gg = fmaf(-2.0f,
                __builtin_amdgcn_rcpf(1.0f + __builtin_amdgcn_exp2f(m[2])), 1.0f);
            const float go = __builtin_amdgcn_rcpf(1.0f + __builtin_amdgcn_exp2f(m[3]));

            c = fmaf(gf, c, gi * gg);
            const float th = fmaf(-2.0f,
                __builtin_amdgcn_rcpf(1.0f + __builtin_amdgcn_exp2f(2.0f * LOG2E * c)), 1.0f);
            const float hj = go * th;

            if (act_lane) *hout = hj;
            hout += hstep;

            // broadcast both sequences' h into wave-uniform copies
            #pragma unroll
            for (int k = 0; k < 20; ++k) {
                shA[k] = __uint_as_float(__builtin_amdgcn_readlane(__float_as_uint(hj), k));
                shB[k] = __uint_as_float(__builtin_amdgcn_readlane(__float_as_uint(hj), 32 + k));
            }
        }
    }
}

// ---------------------------------------------------------------------------
// FC: out[row] = dot(h1[row][0:40], fc_w) + fc_b.  256 rows per block.
// ---------------------------------------------------------------------------
__global__ __launch_bounds__(256) void fc_kernel(
    const float* __restrict__ H1,   // (M, 40)
    const float* __restrict__ Wf,   // (40,)
    const float* __restrict__ Bf,   // (1,)
    float* __restrict__ Out)        // (M,)
{
    __shared__ float ls[256 * 41];
    __shared__ float wl[40];
    const int tid = threadIdx.x;
    const long long row0 = (long long)blockIdx.x * 256;
    const float* src = H1 + row0 * 40;

    #pragma unroll
    for (int it = 0; it < 10; ++it) {
        int i4 = tid + it * 256;
        float4 v = *(const float4*)(src + (long long)i4 * 4);
        int flat = i4 * 4;
        int r = flat / 40, jc = flat - 40 * r;
        float* dp = &ls[r * 41 + jc];
        dp[0] = v.x; dp[1] = v.y; dp[2] = v.z; dp[3] = v.w;
    }
    if (tid < 40) wl[tid] = Wf[tid];
    __syncthreads();

    float acc = Bf[0];
    #pragma unroll
    for (int jc = 0; jc < 40; ++jc)
        acc = fmaf(ls[tid * 41 + jc], wl[jc], acc);
    Out[row0 + tid] = acc;
}

// ---------------------------------------------------------------------------
extern "C" void kernel_launch(void* const* d_in, const int* in_sizes, int n_in,
                              void* d_out, int out_size, void* d_ws, size_t ws_size,
                              hipStream_t stream) {
    const float* x     = (const float*)d_in[0];
    const float* wih0  = (const float*)d_in[1];
    const float* whh0  = (const float*)d_in[2];
    const float* b0    = (const float*)d_in[3];
    const float* wih1  = (const float*)d_in[4];
    const float* whh1  = (const float*)d_in[5];
    const float* b1    = (const float*)d_in[6];
    const float* fcw   = (const float*)d_in[7];
    const float* fcb   = (const float*)d_in[8];
    float* out = (float*)d_out;

    // Workspace layout (floats), with 2048-float pads around xg so the scan's
    // unconditional prefetch (±8 steps = ±1280 floats + lane off) stays in d_ws.
    float* ws = (float*)d_ws;
    float* xg = ws + 2048;                   // B*T*2*80 = 81,920,000 floats
    float* h0 = xg + 81920000LL + 2048;      // B*T*40   = 20,480,000 floats
    float* h1 = h0 + 20480000LL;             // B*T*40   = 20,480,000 floats

    const int M = M_;
    const int gemm_grid = (M + 95) / 96;     // 5334

    // Layer 0
    gemm_xg<80><<<dim3(gemm_grid), dim3(256), 0, stream>>>(x, wih0, b0, xg, M);
    lstm_scan<<<dim3(B_), dim3(64), 0, stream>>>(xg, whh0, h0, T_);
    // Layer 1
    gemm_xg<40><<<dim3(gemm_grid), dim3(256), 0, stream>>>(h0, wih1, b1, xg, M);
    lstm_scan<<<dim3(B_), dim3(64), 0, stream>>>(xg, whh1, h1, T_);
    // FC
    fc_kernel<<<dim3(M / 256), dim3(256), 0, stream>>>(h1, fcw, fcb, out);
}

// Round 7
// 1858.674 us; speedup vs baseline: 1.7286x; 1.0271x over previous
//
#include <hip/hip_runtime.h>
#include <math.h>

// Problem constants
#define B_ 256
#define T_ 2000
#define I_ 80
#define H_ 20
#define G_ 80      // 4*H
#define M_ 512000  // B*T

#define LOG2E 1.442695041f

typedef __attribute__((ext_vector_type(2))) float f32x2;

__device__ __forceinline__ f32x2 mk2(float a, float b) { f32x2 r; r.x = a; r.y = b; return r; }

// ---------------------------------------------------------------------------
// GEMM (layer 0, row-major A): XG[row][d*80 + j*4 + g] =
//   pS_g * (sum_k X[row][k]*Wih[d][k][g*20+j] + B[d][g*20+j])
// ---------------------------------------------------------------------------
template<int K>
__global__ __launch_bounds__(256) void gemm_xg(
    const float* __restrict__ X,     // (M, K) row-major
    const float* __restrict__ Wih,   // (2, K, 80)
    const float* __restrict__ Bias,  // (2, 80)
    float* __restrict__ XG,          // (M, 160) permuted+scaled cols
    int M)
{
    constexpr int KC = 40;
    __shared__ float ws[KC][164];
    __shared__ float xs[KC][100];
    __shared__ float bs[160];

    const int tid  = threadIdx.x;
    const int row0 = blockIdx.x * 96;
    const int tx = tid % 20;
    const int ty = tid / 20;
    const bool run = (ty < 12);

    if (tid < 160) {
        int dd = (tid >= 80);
        int r = tid - 80 * dd;
        int j = r >> 2, g = r & 3;
        float sc = (g == 2) ? 2.0f * LOG2E : -LOG2E;
        bs[tid] = sc * Bias[dd * 80 + g * 20 + j];
    }

    int nrows = M - row0; if (nrows > 96) nrows = 96;

    float acc[8][8];
    bool first = true;

    for (int kc = 0; kc < K; kc += KC) {
        for (int idx = tid; idx < KC * 160; idx += 256) {
            int i = idx / 160, cc = idx - 160 * i;
            int dd = (cc >= 80), r = cc - 80 * dd;
            int j = r >> 2, g = r & 3;
            float sc = (g == 2) ? 2.0f * LOG2E : -LOG2E;
            ws[i][cc] = sc * Wih[(dd * K + kc + i) * 80 + g * 20 + j];
        }
        for (int i4 = tid; i4 < (96 * KC) / 4; i4 += 256) {
            int r = i4 / 10;
            int kk = (i4 - 10 * r) * 4;
            float4 v = make_float4(0.f, 0.f, 0.f, 0.f);
            if (r < nrows)
                v = *(const float4*)(X + (long long)(row0 + r) * K + kc + kk);
            xs[kk][r] = v.x; xs[kk + 1][r] = v.y; xs[kk + 2][r] = v.z; xs[kk + 3][r] = v.w;
        }
        __syncthreads();

        if (first) {
            first = false;
            float bv[8];
            #pragma unroll
            for (int cc = 0; cc < 8; ++cc) bv[cc] = bs[tx * 8 + cc];
            #pragma unroll
            for (int r = 0; r < 8; ++r)
                #pragma unroll
                for (int cc = 0; cc < 8; ++cc) acc[r][cc] = bv[cc];
        }

        if (run) {
            #pragma unroll 4
            for (int k = 0; k < KC; ++k) {
                float a[8], bb[8];
                *(float4*)&a[0]  = *(const float4*)&xs[k][ty * 8];
                *(float4*)&a[4]  = *(const float4*)&xs[k][ty * 8 + 4];
                *(float4*)&bb[0] = *(const float4*)&ws[k][tx * 8];
                *(float4*)&bb[4] = *(const float4*)&ws[k][tx * 8 + 4];
                #pragma unroll
                for (int r = 0; r < 8; ++r)
                    #pragma unroll
                    for (int cc = 0; cc < 8; ++cc)
                        acc[r][cc] = fmaf(a[r], bb[cc], acc[r][cc]);
            }
        }
        __syncthreads();
    }

    if (run) {
        #pragma unroll
        for (int r = 0; r < 8; ++r) {
            int row = row0 + ty * 8 + r;
            if (row < M) {
                float* dst = XG + (long long)row * 160 + tx * 8;
                *(float4*)(dst)     = *(float4*)&acc[r][0];
                *(float4*)(dst + 4) = *(float4*)&acc[r][4];
            }
        }
    }
}

// ---------------------------------------------------------------------------
// GEMM (layer 1, TRANSPOSED A): A[row=(b,t)][k] = H0t[(b*40+k)*T + t]
// K=40. Tiles never straddle batches: grid = B * 21, tile = (b, t0..t0+95).
// Staging loads float4 along t (contiguous) — fully coalesced.
// ---------------------------------------------------------------------------
__global__ __launch_bounds__(256) void gemm_xg_tA(
    const float* __restrict__ H0t,   // (B, 40, T)
    const float* __restrict__ Wih,   // (2, 40, 80)
    const float* __restrict__ Bias,  // (2, 80)
    float* __restrict__ XG,          // (M, 160) permuted+scaled cols
    int T)
{
    constexpr int K = 40;
    __shared__ float ws[K][164];
    __shared__ float xs[K][100];
    __shared__ float bs[160];

    const int tid = threadIdx.x;
    const int bb  = blockIdx.x / 21;
    const int tc  = blockIdx.x % 21;
    const int t0  = tc * 96;
    const int tx  = tid % 20;
    const int ty  = tid / 20;
    const bool run = (ty < 12);

    if (tid < 160) {
        int dd = (tid >= 80);
        int r = tid - 80 * dd;
        int j = r >> 2, g = r & 3;
        float sc = (g == 2) ? 2.0f * LOG2E : -LOG2E;
        bs[tid] = sc * Bias[dd * 80 + g * 20 + j];
    }

    int nrows = T - t0; if (nrows > 96) nrows = 96;   // 96 or 80 (both %4==0)

    // stage weights (single K-chunk)
    for (int idx = tid; idx < K * 160; idx += 256) {
        int i = idx / 160, cc = idx - 160 * i;
        int dd = (cc >= 80), r = cc - 80 * dd;
        int j = r >> 2, g = r & 3;
        float sc = (g == 2) ? 2.0f * LOG2E : -LOG2E;
        ws[i][cc] = sc * Wih[(dd * K + i) * 80 + g * 20 + j];
    }
    // stage A^T: xs[k][r] = H0t[(bb*40+k)*T + t0 + r], float4 along r(=t)
    for (int i4 = tid; i4 < K * 24; i4 += 256) {
        int k = i4 / 24;
        int r = (i4 - 24 * k) * 4;
        float4 v = make_float4(0.f, 0.f, 0.f, 0.f);
        if (r < nrows)
            v = *(const float4*)(H0t + ((long long)bb * 40 + k) * T + t0 + r);
        *(float4*)&xs[k][r] = v;
    }
    __syncthreads();

    float acc[8][8];
    {
        float bv[8];
        #pragma unroll
        for (int cc = 0; cc < 8; ++cc) bv[cc] = bs[tx * 8 + cc];
        #pragma unroll
        for (int r = 0; r < 8; ++r)
            #pragma unroll
            for (int cc = 0; cc < 8; ++cc) acc[r][cc] = bv[cc];
    }

    if (run) {
        #pragma unroll 4
        for (int k = 0; k < K; ++k) {
            float a[8], bb2[8];
            *(float4*)&a[0]   = *(const float4*)&xs[k][ty * 8];
            *(float4*)&a[4]   = *(const float4*)&xs[k][ty * 8 + 4];
            *(float4*)&bb2[0] = *(const float4*)&ws[k][tx * 8];
            *(float4*)&bb2[4] = *(const float4*)&ws[k][tx * 8 + 4];
            #pragma unroll
            for (int r = 0; r < 8; ++r)
                #pragma unroll
                for (int cc = 0; cc < 8; ++cc)
                    acc[r][cc] = fmaf(a[r], bb2[cc], acc[r][cc]);
        }

        #pragma unroll
        for (int r = 0; r < 8; ++r) {
            int rr = ty * 8 + r;
            if (rr < nrows) {
                long long row = (long long)bb * T + t0 + rr;
                float* dst = XG + row * 160 + tx * 8;
                *(float4*)(dst)     = *(float4*)&acc[r][0];
                *(float4*)(dst + 4) = *(float4*)&acc[r][4];
            }
        }
    }
}

// ---------------------------------------------------------------------------
// LSTM scan v7 = v6 + BATCHED TRANSPOSED h stores.
// h kept in 4 registers, ONE float4 store per 4 steps to h_out (B, 40, T)
// (contiguous along t per unit) — 4x fewer store events in the vm queue,
// store clusters separated from the prefetch-load clusters.
// Everything else identical to v6.
// ---------------------------------------------------------------------------
__attribute__((amdgpu_waves_per_eu(1)))
__global__ __launch_bounds__(64) void lstm_scan(
    const float* __restrict__ xg,    // (B,T,2,20,4) scaled, unit-major
    const float* __restrict__ w_hh,  // (2, 20, 80) natural (k, g*20+j)
    float* __restrict__ h_out,       // (B, 40, T): [(b*40 + d*20 + j)*T + t]
    int T)
{
    const int b    = blockIdx.x;          // 0..255
    const int lane = threadIdx.x & 63;
    const int d    = lane >> 5;           // 0 = fwd (lanes 0-31), 1 = bwd
    const int j    = lane & 31;
    const bool act_lane = (j < H_);
    const int jj   = act_lane ? j : 0;
    const bool isB = (d == 1);

    // Pre-scaled packed recurrent weights (per-half values in same registers)
    f32x2 w[4][10];
    const float* wb = w_hh + d * (H_ * G_);
    #pragma unroll
    for (int g = 0; g < 4; ++g) {
        const float sc = (g == 2) ? 2.0f * LOG2E : -LOG2E;
        #pragma unroll
        for (int i = 0; i < 10; ++i)
            w[g][i] = mk2(sc * wb[(2 * i) * G_ + g * 20 + jj],
                          sc * wb[(2 * i + 1) * G_ + g * 20 + jj]);
    }

    // Wave-uniform h for both sequences (SGPRs via readlane)
    float shA[20], shB[20];
    #pragma unroll
    for (int k = 0; k < 20; ++k) { shA[k] = 0.f; shB[k] = 0.f; }
    float c = 0.f;

    const int t0    = isB ? (T - 1) : 0;
    const int rstep = isB ? -160 : 160;
    const float* pf = xg + ((long long)(b * T + t0) * 2 + d) * 80 + 4 * jj;

    // transposed h store pointer: group of 4 t's, 16B aligned
    float* hp = h_out + ((long long)b * 40 + d * 20 + jj) * T + (isB ? T - 4 : 0);
    const int hgstep = isB ? -4 : 4;

    constexpr int PF = 8;
    float4 px[PF];
    #pragma unroll
    for (int s = 0; s < PF; ++s) { px[s] = *(const float4*)pf; pf += rstep; }

    float hq0 = 0.f, hq1 = 0.f, hq2 = 0.f, hq3 = 0.f;

    for (int tb = 0; tb < T; tb += PF) {
        #pragma unroll
        for (int s = 0; s < PF; ++s) {
            const float4 v = px[s];
            px[s] = *(const float4*)pf; pf += rstep;   // prefetch t+PF

            // 8 independent pk-chains (4 gates x 2 seqs), depth 10
            f32x2 aA[4], aB[4];
            aA[0] = mk2(v.x, 0.f); aA[1] = mk2(v.y, 0.f);
            aA[2] = mk2(v.z, 0.f); aA[3] = mk2(v.w, 0.f);
            #pragma unroll
            for (int g = 0; g < 4; ++g) aB[g] = aA[g];
            #pragma unroll
            for (int i = 0; i < 10; ++i) {
                const f32x2 ha = mk2(shA[2 * i], shA[2 * i + 1]);
                const f32x2 hb = mk2(shB[2 * i], shB[2 * i + 1]);
                #pragma unroll
                for (int g = 0; g < 4; ++g) {
                    aA[g] = __builtin_elementwise_fma(w[g][i], ha, aA[g]);
                    aB[g] = __builtin_elementwise_fma(w[g][i], hb, aB[g]);
                }
            }
            float m[4];
            #pragma unroll
            for (int g = 0; g < 4; ++g) {
                const float sA = aA[g].x + aA[g].y;
                const float sB = aB[g].x + aB[g].y;
                m[g] = isB ? sB : sA;
            }

            const float gi = __builtin_amdgcn_rcpf(1.0f + __builtin_amdgcn_exp2f(m[0]));
            const float gf = __builtin_amdgcn_rcpf(1.0f + __builtin_amdgcn_exp2f(m[1]));
            const float gg = fmaf(-2.0f,
                __builtin_amdgcn_rcpf(1.0f + __builtin_amdgcn_exp2f(m[2])), 1.0f);
            const float go = __builtin_amdgcn_rcpf(1.0f + __builtin_amdgcn_exp2f(m[3]));

            c = fmaf(gf, c, gi * gg);
            const float th = fmaf(-2.0f,
                __builtin_amdgcn_rcpf(1.0f + __builtin_amdgcn_exp2f(2.0f * LOG2E * c)), 1.0f);
            const float hj = go * th;

            // buffer h (phase = s&3); one float4 store per 4 steps
            if constexpr (true) {
                const int p = s & 3;
                if (p == 0) hq0 = hj;
                else if (p == 1) hq1 = hj;
                else if (p == 2) hq2 = hj;
                else {
                    hq3 = hj;
                    float4 sv;   // bwd wrote t descending -> reverse for memory order
                    sv.x = isB ? hq3 : hq0;
                    sv.y = isB ? hq2 : hq1;
                    sv.z = isB ? hq1 : hq2;
                    sv.w = isB ? hq0 : hq3;
                    if (act_lane) *(float4*)hp = sv;
                    hp += hgstep;
                }
            }

            // broadcast both sequences' h into wave-uniform copies
            #pragma unroll
            for (int k = 0; k < 20; ++k) {
                shA[k] = __uint_as_float(__builtin_amdgcn_readlane(__float_as_uint(hj), k));
                shB[k] = __uint_as_float(__builtin_amdgcn_readlane(__float_as_uint(hj), 32 + k));
            }
        }
    }
}

// ---------------------------------------------------------------------------
// FC over transposed h: out[b*T+t] = sum_u H1t[(b*40+u)*T+t]*w[u] + bias.
// Fully coalesced float4 along t. grid (B, 2): chunk c covers t in
// [c*1024, ...): c=0 -> 256 threads x4, c=1 -> 244 threads x4 (total 2000).
// ---------------------------------------------------------------------------
__global__ __launch_bounds__(256) void fc_t(
    const float* __restrict__ H1t,  // (B, 40, T)
    const float* __restrict__ Wf,   // (40,)
    const float* __restrict__ Bf,   // (1,)
    float* __restrict__ Out,        // (B, T)
    int T)
{
    const int b   = blockIdx.x;
    const int t   = blockIdx.y * 1024 + threadIdx.x * 4;
    if (t + 3 >= T + 3) return;      // t <= T-4 guard below
    if (t > T - 4) return;

    const float bias = Bf[0];
    float4 acc = make_float4(bias, bias, bias, bias);
    const float* base = H1t + (long long)b * 40 * T + t;
    #pragma unroll 8
    for (int u = 0; u < 40; ++u) {
        const float wv = Wf[u];
        const float4 hv = *(const float4*)(base + (long long)u * T);
        acc.x = fmaf(hv.x, wv, acc.x);
        acc.y = fmaf(hv.y, wv, acc.y);
        acc.z = fmaf(hv.z, wv, acc.z);
        acc.w = fmaf(hv.w, wv, acc.w);
    }
    *(float4*)(Out + (long long)b * T + t) = acc;
}

// ---------------------------------------------------------------------------
extern "C" void kernel_launch(void* const* d_in, const int* in_sizes, int n_in,
                              void* d_out, int out_size, void* d_ws, size_t ws_size,
                              hipStream_t stream) {
    const float* x     = (const float*)d_in[0];
    const float* wih0  = (const float*)d_in[1];
    const float* whh0  = (const float*)d_in[2];
    const float* b0    = (const float*)d_in[3];
    const float* wih1  = (const float*)d_in[4];
    const float* whh1  = (const float*)d_in[5];
    const float* b1    = (const float*)d_in[6];
    const float* fcw   = (const float*)d_in[7];
    const float* fcb   = (const float*)d_in[8];
    float* out = (float*)d_out;

    // Workspace (floats): 2048-float pads around xg for the scan's
    // unconditional ±8-step prefetch.
    float* ws = (float*)d_ws;
    float* xg  = ws + 2048;                  // B*T*2*80 = 81,920,000 floats
    float* h0t = xg + 81920000LL + 2048;     // B*40*T   = 20,480,000 floats
    float* h1t = h0t + 20480000LL;           // B*40*T   = 20,480,000 floats

    const int M = M_;
    const int gemm_grid = (M + 95) / 96;     // 5334

    // Layer 0 (row-major A)
    gemm_xg<80><<<dim3(gemm_grid), dim3(256), 0, stream>>>(x, wih0, b0, xg, M);
    lstm_scan<<<dim3(B_), dim3(64), 0, stream>>>(xg, whh0, h0t, T_);
    // Layer 1 (transposed A)
    gemm_xg_tA<<<dim3(B_ * 21), dim3(256), 0, stream>>>(h0t, wih1, b1, xg, T_);
    lstm_scan<<<dim3(B_), dim3(64), 0, stream>>>(xg, whh1, h1t, T_);
    // FC (transposed input, coalesced)
    fc_t<<<dim3(B_, 2), dim3(256), 0, stream>>>(h1t, fcw, fcb, out, T_);
}